// Round 9
// baseline (153.576 us; speedup 1.0000x reference)
//
#include <hip/hip_runtime.h>
#include <hip/hip_bf16.h>

typedef short bf16x8 __attribute__((ext_vector_type(8)));
typedef short bf16x4 __attribute__((ext_vector_type(4)));
typedef float f32x4  __attribute__((ext_vector_type(4)));

__device__ __forceinline__ unsigned short f2bf(float f) {
    union { float fv; unsigned int u; } v; v.fv = f;
    unsigned int r = v.u + 0x7FFFu + ((v.u >> 16) & 1u);
    return (unsigned short)(r >> 16);
}

__device__ __forceinline__ short f2bf_n(float f) {
    union { __hip_bfloat16 h; short s; } u;
    u.h = __float2bfloat16(f);
    return u.s;
}

__device__ __forceinline__ void gload16(const short* g, short* l) {
    __builtin_amdgcn_global_load_lds(
        (const __attribute__((address_space(1))) void*)g,
        (__attribute__((address_space(3))) void*)l, 16, 0, 0);
}

// ---- convert x f32 -> bf16, 8 elems/thread ----
__global__ __launch_bounds__(256) void cvt_x(
    const float* __restrict__ x, short* __restrict__ xb)
{
    size_t i = ((size_t)blockIdx.x * 256 + threadIdx.x) * 8;
    f32x4 a = *(const f32x4*)(x + i);
    f32x4 b = *(const f32x4*)(x + i + 4);
    bf16x8 s;
    #pragma unroll
    for (int e = 0; e < 4; ++e) { s[e] = (short)f2bf(a[e]); s[4 + e] = (short)f2bf(b[e]); }
    *(bf16x8*)(xb + i) = s;
}

// ---- tiled transpose (both weights in one launch): f32 [K][N] -> bf16 [N][K]
__global__ __launch_bounds__(256) void tr_w2(
    const float* __restrict__ Wqkv, const float* __restrict__ Wout,
    short* __restrict__ Wqkvt, short* __restrict__ Woutt)
{
    __shared__ float tile[32][33];
    const int b = blockIdx.x;
    const float* src; short* dst; int N, bb;
    if (b < 768) { src = Wqkv; dst = Wqkvt; N = 1536; bb = b; }
    else         { src = Wout; dst = Woutt; N = 512;  bb = b - 768; }
    const int tx = threadIdx.x;
    const int nb = N >> 5;
    const int k0 = (bb / nb) * 32;
    const int n0 = (bb % nb) * 32;
    const int r  = tx >> 3;
    const int c4 = (tx & 7) * 4;
    f32x4 v = *(const f32x4*)(src + (size_t)(k0 + r) * N + n0 + c4);
    #pragma unroll
    for (int e = 0; e < 4; ++e) tile[r][c4 + e] = v[e];
    __syncthreads();
    bf16x4 o;
    #pragma unroll
    for (int e = 0; e < 4; ++e) o[e] = (short)f2bf(tile[c4 + e][r]);
    *(bf16x4*)(dst + (size_t)(n0 + r) * 512 + k0 + c4) = o;
}

// ---- GEMM: 128x128 tile, double-buffered LDS, counted vmcnt prefetch ----
template<int F32OUT>
__global__ __launch_bounds__(256, 2) void gemm_db(
    const short* __restrict__ A, const short* __restrict__ Bt,
    short* __restrict__ Cb, float* __restrict__ Cf, const float* __restrict__ bias,
    int M, int N, int K, int NB)
{
    __shared__ short lds[2][2][128 * 64];   // [buf][A|B][row*64+chunk*8]
    const int t    = threadIdx.x;
    const int lane = t & 63;
    const int wid  = t >> 6;
    const int l15  = lane & 15;
    const int lg   = lane >> 4;

    const int cpx = gridDim.x >> 3;
    const int swz = (blockIdx.x & 7) * cpx + (blockIdx.x >> 3);
    const int m0 = (swz / NB) * 128;
    const int n0 = (swz % NB) * 128;

    const int wm = (wid >> 1) * 64;
    const int wn = (wid & 1) * 64;

    const int scol = 8 * ((lane & 7) ^ ((lane >> 3) & 7));

    float bval[4];
    if constexpr (F32OUT) {
        #pragma unroll
        for (int ni = 0; ni < 4; ++ni) bval[ni] = bias[n0 + wn + ni * 16 + l15];
    }

    f32x4 acc[4][4];
    #pragma unroll
    for (int i = 0; i < 4; ++i)
        #pragma unroll
        for (int j = 0; j < 4; ++j)
            acc[i][j] = f32x4{0.f, 0.f, 0.f, 0.f};

    const int NT = K >> 6;

    auto stage = [&](int buf, int tk) {
        #pragma unroll
        for (int j = 0; j < 4; ++j) {
            const int r = wid * 32 + j * 8 + (lane >> 3);
            gload16(A  + (size_t)(m0 + r) * K + tk * 64 + scol,
                    &lds[buf][0][(wid * 32 + j * 8) * 64]);
            gload16(Bt + (size_t)(n0 + r) * K + tk * 64 + scol,
                    &lds[buf][1][(wid * 32 + j * 8) * 64]);
        }
    };

    stage(0, 0);

    for (int tk = 0; tk < NT; ++tk) {
        const int cur = tk & 1;
        if (tk + 1 < NT) {
            stage(cur ^ 1, tk + 1);
            asm volatile("s_waitcnt vmcnt(8)" ::: "memory");
        } else {
            asm volatile("s_waitcnt vmcnt(0)" ::: "memory");
        }
        __builtin_amdgcn_s_barrier();

        bf16x8 af[4][2], bg[4][2];
        #pragma unroll
        for (int kk = 0; kk < 2; ++kk) {
            #pragma unroll
            for (int mi = 0; mi < 4; ++mi)
                af[mi][kk] = *(const bf16x8*)&lds[cur][0][
                    (wm + mi * 16 + l15) * 64 + (((kk * 4 + lg) ^ (l15 & 7)) * 8)];
            #pragma unroll
            for (int ni = 0; ni < 4; ++ni)
                bg[ni][kk] = *(const bf16x8*)&lds[cur][1][
                    (wn + ni * 16 + l15) * 64 + (((kk * 4 + lg) ^ (l15 & 7)) * 8)];
        }

        __builtin_amdgcn_s_setprio(1);
        #pragma unroll
        for (int kk = 0; kk < 2; ++kk)
            #pragma unroll
            for (int mi = 0; mi < 4; ++mi)
                #pragma unroll
                for (int ni = 0; ni < 4; ++ni)
                    acc[mi][ni] = __builtin_amdgcn_mfma_f32_16x16x32_bf16(
                        af[mi][kk], bg[ni][kk], acc[mi][ni], 0, 0, 0);
        __builtin_amdgcn_s_setprio(0);
        __builtin_amdgcn_s_barrier();
    }

    #pragma unroll
    for (int mi = 0; mi < 4; ++mi) {
        #pragma unroll
        for (int ni = 0; ni < 4; ++ni) {
            const int col = n0 + wn + ni * 16 + l15;
            #pragma unroll
            for (int r = 0; r < 4; ++r) {
                const int rowi = m0 + wm + mi * 16 + 4 * lg + r;
                if constexpr (F32OUT) {
                    Cf[(size_t)rowi * N + col] = acc[mi][ni][r] + bval[ni];
                } else {
                    Cb[(size_t)rowi * N + col] = (short)f2bf(acc[mi][ni][r]);
                }
            }
        }
    }
}

// ---- fused attention, T15 cross-tile pipeline: grid 512, 8 waves x 32 q-rows.
// Per tile t: [scatter V(t) -> Vt[t%3]] barrier [issue K/V loads t+1]
//             QK(t)->stCur  then  {softmax+PV}(t-1) on stPrev  (MFMA||VALU).
// K: double-buffered global_load_lds (chunk-XOR swizzle both sides); the
//    vreg-wait before the barrier implies (vmcnt FIFO) the K DMA landed.
// V: TRIPLE-buffered (PV(t) reads happen one body after the write; the next
//    write of that buffer is at t+3, with a barrier at t+2 in between).
// stA/stB are statically named (rule #20: no runtime-indexed reg arrays).
__global__ __launch_bounds__(512, 4) void attn_kernel(
    const short* __restrict__ qkv, short* __restrict__ attn_out)
{
    __shared__ short Kl[2][4096];    // [kv][64] linear, chunk-swizzled (16KB)
    __shared__ short Vt[3][5120];    // [d][80] octet-swizzled (30KB)
    const int t    = threadIdx.x;
    const int lane = t & 63;
    const int wid  = t >> 6;
    const int l15  = lane & 15;
    const int lg   = lane >> 4;
    const int pairid = blockIdx.x & 255;
    const int qh  = blockIdx.x >> 8;
    const int bp  = pairid >> 3;
    const int h   = pairid & 7;
    const size_t tok0 = (size_t)bp * 512;
    const int q0   = qh * 256 + wid * 32;
    const int qcol = h * 64;

    bf16x8 qf[2][2];
    #pragma unroll
    for (int mj = 0; mj < 2; ++mj)
        #pragma unroll
        for (int kf = 0; kf < 2; ++kf)
            qf[mj][kf] = *(const bf16x8*)(qkv + (tok0 + q0 + mj * 16 + l15) * 1536
                                          + qcol + kf * 32 + 8 * lg);

    f32x4 ot[4][2];
    #pragma unroll
    for (int i = 0; i < 4; ++i)
        #pragma unroll
        for (int j = 0; j < 2; ++j)
            ot[i][j] = f32x4{0.f, 0.f, 0.f, 0.f};
    float mrun[2] = {-1e30f, -1e30f}, lrun[2] = {0.f, 0.f};

    const int krow = t >> 3;
    const short* Ksrc0 = qkv + (tok0 + krow) * 1536 + 512 + qcol
                         + 8 * ((t & 7) ^ (krow & 7));
    const int sn = t >> 3;
    const int sd = (t & 7) * 8;
    const short* Vsrc0 = qkv + (tok0 + sn) * 1536 + 1024 + qcol + sd;
    const int kvp = (sn & 7) | (((sn >> 3) ^ (t & 7)) << 3);

    gload16(Ksrc0, &Kl[0][t * 8]);
    bf16x8 vreg = *(const bf16x8*)(Vsrc0);

    const float C = 0.18033688011112042f;   // 0.125 * log2(e)

    f32x4 stA[4][2], stB[4][2];

#define SMPV(ST, TP)                                                          \
    {                                                                         \
        const short* vsrc = &Vt[(TP) % 3][0];                                 \
        _Pragma("unroll")                                                     \
        for (int mj = 0; mj < 2; ++mj) {                                      \
            float pm = -1e30f;                                                \
            _Pragma("unroll")                                                 \
            for (int ni = 0; ni < 4; ++ni)                                    \
                _Pragma("unroll")                                             \
                for (int r = 0; r < 4; ++r)                                   \
                    pm = fmaxf(pm, ST[ni][mj][r]);                            \
            pm = fmaxf(pm, __shfl_xor(pm, 16));                               \
            pm = fmaxf(pm, __shfl_xor(pm, 32));                               \
            pm *= C;                                                          \
            if (!__all(pm <= mrun[mj] + 8.f)) {                               \
                const float mnew = fmaxf(mrun[mj], pm);                       \
                const float fsc  = __builtin_amdgcn_exp2f(mrun[mj] - mnew);   \
                lrun[mj] *= fsc;                                              \
                _Pragma("unroll")                                             \
                for (int di = 0; di < 4; ++di) ot[di][mj] *= fsc;             \
                mrun[mj] = mnew;                                              \
            }                                                                 \
            float ps = 0.f;                                                   \
            _Pragma("unroll")                                                 \
            for (int ni = 0; ni < 4; ++ni)                                    \
                _Pragma("unroll")                                             \
                for (int r = 0; r < 4; ++r) {                                 \
                    float e = __builtin_amdgcn_exp2f(                         \
                        __builtin_fmaf(ST[ni][mj][r], C, -mrun[mj]));         \
                    ST[ni][mj][r] = e;                                        \
                    ps += e;                                                  \
                }                                                             \
            ps += __shfl_xor(ps, 16);                                         \
            ps += __shfl_xor(ps, 32);                                         \
            lrun[mj] += ps;                                                   \
        }                                                                     \
        __builtin_amdgcn_s_setprio(1);                                        \
        _Pragma("unroll")                                                     \
        for (int ni = 0; ni < 4; ++ni) {                                      \
            bf16x4 pb[2];                                                     \
            _Pragma("unroll")                                                 \
            for (int mj = 0; mj < 2; ++mj)                                    \
                _Pragma("unroll")                                             \
                for (int r = 0; r < 4; ++r)                                   \
                    pb[mj][r] = f2bf_n(ST[ni][mj][r]);                        \
            _Pragma("unroll")                                                 \
            for (int di = 0; di < 4; ++di) {                                  \
                bf16x4 av = *(const bf16x4*)&vsrc[                            \
                    (di * 16 + l15) * 80                                      \
                    + (((2 * ni + (lg >> 1)) ^ (2 * di + (l15 >> 3))) * 8)    \
                    + 4 * (lg & 1)];                                          \
                _Pragma("unroll")                                             \
                for (int mj = 0; mj < 2; ++mj)                                \
                    ot[di][mj] = __builtin_amdgcn_mfma_f32_16x16x16bf16_1k(   \
                        av, pb[mj], ot[di][mj], 0, 0, 0);                     \
            }                                                                 \
        }                                                                     \
        __builtin_amdgcn_s_setprio(0);                                        \
    }

#define BODY(T, SCUR, SPRV)                                                   \
    {                                                                         \
        short* vdst = &Vt[(T) % 3][0];                                        \
        _Pragma("unroll")                                                     \
        for (int i = 0; i < 8; ++i) vdst[(sd + i) * 80 + kvp] = vreg[i];      \
        __syncthreads();                                                      \
        if ((T) < 7) {                                                        \
            gload16(Ksrc0 + (size_t)((T) + 1) * 64 * 1536,                    \
                    &Kl[((T) + 1) & 1][t * 8]);                               \
            vreg = *(const bf16x8*)(Vsrc0 + (size_t)((T) + 1) * 64 * 1536);   \
        }                                                                     \
        _Pragma("unroll")                                                     \
        for (int i = 0; i < 4; ++i)                                           \
            _Pragma("unroll")                                                 \
            for (int j = 0; j < 2; ++j)                                       \
                SCUR[i][j] = f32x4{0.f, 0.f, 0.f, 0.f};                       \
        __builtin_amdgcn_s_setprio(1);                                        \
        _Pragma("unroll")                                                     \
        for (int kf = 0; kf < 2; ++kf) {                                      \
            _Pragma("unroll")                                                 \
            for (int ni = 0; ni < 4; ++ni) {                                  \
                bf16x8 kfr = *(const bf16x8*)&Kl[(T) & 1][                    \
                    (ni * 16 + l15) * 64 + (((kf * 4 + lg) ^ (l15 & 7)) * 8)];\
                _Pragma("unroll")                                             \
                for (int mj = 0; mj < 2; ++mj)                                \
                    SCUR[ni][mj] = __builtin_amdgcn_mfma_f32_16x16x32_bf16(   \
                        kfr, qf[mj][kf], SCUR[ni][mj], 0, 0, 0);              \
            }                                                                 \
        }                                                                     \
        __builtin_amdgcn_s_setprio(0);                                        \
        if ((T) > 0) SMPV(SPRV, (T) - 1);                                     \
    }

    for (int t2 = 0; t2 < 8; t2 += 2) {
        BODY(t2, stA, stB);
        BODY(t2 + 1, stB, stA);
    }
    SMPV(stB, 7);
#undef BODY
#undef SMPV

    float inv[2];
    #pragma unroll
    for (int mj = 0; mj < 2; ++mj) inv[mj] = 1.f / lrun[mj];
    #pragma unroll
    for (int di = 0; di < 4; ++di)
        #pragma unroll
        for (int mj = 0; mj < 2; ++mj) {
            const size_t tok = tok0 + q0 + mj * 16 + l15;
            const int col = qcol + di * 16 + 4 * lg;
            bf16x4 o4;
            #pragma unroll
            for (int r = 0; r < 4; ++r)
                o4[r] = f2bf_n(ot[di][mj][r] * inv[mj]);
            *(bf16x4*)(attn_out + tok * 512 + col) = o4;
        }
}

extern "C" void kernel_launch(void* const* d_in, const int* in_sizes, int n_in,
                              void* d_out, int out_size, void* d_ws, size_t ws_size,
                              hipStream_t stream) {
    const float* x    = (const float*)d_in[0];   // [16384][512]
    const float* Wqkv = (const float*)d_in[1];   // [512][1536]
    const float* Wout = (const float*)d_in[2];   // [512][512]
    const float* bout = (const float*)d_in[3];   // [512]
    float* out = (float*)d_out;                  // [16384][512] f32

    char* ws = (char*)d_ws;
    short* qkvb  = (short*)(ws);                 // 48 MB  [16384][1536] bf16
    short* xb    = (short*)(ws + 50331648ull);   // 16 MB  [16384][512]  bf16 (x)
    short* attnb = xb;                           // reuse: xb dead before attn writes
    short* Wqkvt = (short*)(ws + 67108864ull);   // 1.5 MB [1536][512]   bf16
    short* Woutt = (short*)(ws + 68681728ull);   // 0.5 MB [512][512]    bf16

    cvt_x<<<4096, 256, 0, stream>>>(x, xb);
    tr_w2<<<1024, 256, 0, stream>>>(Wqkv, Wout, Wqkvt, Woutt);

    // M=16384 (128 mb) x N=1536 (12 nb) -> 1536 blocks (N fastest)
    gemm_db<0><<<1536, 256, 0, stream>>>(xb, Wqkvt, qkvb, nullptr, nullptr,
                                         16384, 1536, 512, 12);

    attn_kernel<<<512, 512, 0, stream>>>(qkvb, attnb);

    // M=16384 (128 mb) x N=512 (4 nb) -> 512 blocks
    gemm_db<1><<<512, 256, 0, stream>>>(attnb, Woutt, nullptr, out, bout,
                                        16384, 512, 512, 4);
}

// Round 10
// 96.141 us; speedup vs baseline: 1.5974x; 1.5974x over previous
//
#include <hip/hip_runtime.h>
#include <hip/hip_bf16.h>

typedef short bf16x8 __attribute__((ext_vector_type(8)));
typedef short bf16x4 __attribute__((ext_vector_type(4)));
typedef float f32x4  __attribute__((ext_vector_type(4)));

__device__ __forceinline__ unsigned short f2bf(float f) {
    union { float fv; unsigned int u; } v; v.fv = f;
    unsigned int r = v.u + 0x7FFFu + ((v.u >> 16) & 1u);
    return (unsigned short)(r >> 16);
}

__device__ __forceinline__ short f2bf_n(float f) {
    union { __hip_bfloat16 h; short s; } u;
    u.h = __float2bfloat16(f);
    return u.s;
}

__device__ __forceinline__ void gload16(const short* g, short* l) {
    __builtin_amdgcn_global_load_lds(
        (const __attribute__((address_space(1))) void*)g,
        (__attribute__((address_space(3))) void*)l, 16, 0, 0);
}

// ---- merged prep: blocks 0..4095 convert x f32->bf16 (8 elems/thread);
//      blocks 4096..5119 transpose+convert the two weight matrices ----
__global__ __launch_bounds__(256) void prep_all(
    const float* __restrict__ x, short* __restrict__ xb,
    const float* __restrict__ Wqkv, const float* __restrict__ Wout,
    short* __restrict__ Wqkvt, short* __restrict__ Woutt)
{
    if (blockIdx.x < 4096) {
        size_t i = ((size_t)blockIdx.x * 256 + threadIdx.x) * 8;
        f32x4 a = *(const f32x4*)(x + i);
        f32x4 b = *(const f32x4*)(x + i + 4);
        bf16x8 s;
        #pragma unroll
        for (int e = 0; e < 4; ++e) { s[e] = (short)f2bf(a[e]); s[4 + e] = (short)f2bf(b[e]); }
        *(bf16x8*)(xb + i) = s;
        return;
    }
    __shared__ float tile[32][33];
    const int b = blockIdx.x - 4096;
    const float* src; short* dst; int N, bb;
    if (b < 768) { src = Wqkv; dst = Wqkvt; N = 1536; bb = b; }
    else         { src = Wout; dst = Woutt; N = 512;  bb = b - 768; }
    const int tx = threadIdx.x;
    const int nb = N >> 5;
    const int k0 = (bb / nb) * 32;
    const int n0 = (bb % nb) * 32;
    const int r  = tx >> 3;
    const int c4 = (tx & 7) * 4;
    f32x4 v = *(const f32x4*)(src + (size_t)(k0 + r) * N + n0 + c4);
    #pragma unroll
    for (int e = 0; e < 4; ++e) tile[r][c4 + e] = v[e];
    __syncthreads();
    bf16x4 o;
    #pragma unroll
    for (int e = 0; e < 4; ++e) o[e] = (short)f2bf(tile[c4 + e][r]);
    *(bf16x4*)(dst + (size_t)(n0 + r) * 512 + k0 + c4) = o;
}

// ---- GEMM: 128x128 tile, double-buffered LDS, counted vmcnt prefetch ----
template<int F32OUT>
__global__ __launch_bounds__(256, 2) void gemm_db(
    const short* __restrict__ A, const short* __restrict__ Bt,
    short* __restrict__ Cb, float* __restrict__ Cf, const float* __restrict__ bias,
    int M, int N, int K, int NB)
{
    __shared__ short lds[2][2][128 * 64];   // [buf][A|B][row*64+chunk*8]
    const int t    = threadIdx.x;
    const int lane = t & 63;
    const int wid  = t >> 6;
    const int l15  = lane & 15;
    const int lg   = lane >> 4;

    const int cpx = gridDim.x >> 3;
    const int swz = (blockIdx.x & 7) * cpx + (blockIdx.x >> 3);
    const int m0 = (swz / NB) * 128;
    const int n0 = (swz % NB) * 128;

    const int wm = (wid >> 1) * 64;
    const int wn = (wid & 1) * 64;

    const int scol = 8 * ((lane & 7) ^ ((lane >> 3) & 7));

    float bval[4];
    if constexpr (F32OUT) {
        #pragma unroll
        for (int ni = 0; ni < 4; ++ni) bval[ni] = bias[n0 + wn + ni * 16 + l15];
    }

    f32x4 acc[4][4];
    #pragma unroll
    for (int i = 0; i < 4; ++i)
        #pragma unroll
        for (int j = 0; j < 4; ++j)
            acc[i][j] = f32x4{0.f, 0.f, 0.f, 0.f};

    const int NT = K >> 6;

    auto stage = [&](int buf, int tk) {
        #pragma unroll
        for (int j = 0; j < 4; ++j) {
            const int r = wid * 32 + j * 8 + (lane >> 3);
            gload16(A  + (size_t)(m0 + r) * K + tk * 64 + scol,
                    &lds[buf][0][(wid * 32 + j * 8) * 64]);
            gload16(Bt + (size_t)(n0 + r) * K + tk * 64 + scol,
                    &lds[buf][1][(wid * 32 + j * 8) * 64]);
        }
    };

    stage(0, 0);

    for (int tk = 0; tk < NT; ++tk) {
        const int cur = tk & 1;
        if (tk + 1 < NT) {
            stage(cur ^ 1, tk + 1);
            asm volatile("s_waitcnt vmcnt(8)" ::: "memory");
        } else {
            asm volatile("s_waitcnt vmcnt(0)" ::: "memory");
        }
        __builtin_amdgcn_s_barrier();

        bf16x8 af[4][2], bg[4][2];
        #pragma unroll
        for (int kk = 0; kk < 2; ++kk) {
            #pragma unroll
            for (int mi = 0; mi < 4; ++mi)
                af[mi][kk] = *(const bf16x8*)&lds[cur][0][
                    (wm + mi * 16 + l15) * 64 + (((kk * 4 + lg) ^ (l15 & 7)) * 8)];
            #pragma unroll
            for (int ni = 0; ni < 4; ++ni)
                bg[ni][kk] = *(const bf16x8*)&lds[cur][1][
                    (wn + ni * 16 + l15) * 64 + (((kk * 4 + lg) ^ (l15 & 7)) * 8)];
        }

        __builtin_amdgcn_s_setprio(1);
        #pragma unroll
        for (int kk = 0; kk < 2; ++kk)
            #pragma unroll
            for (int mi = 0; mi < 4; ++mi)
                #pragma unroll
                for (int ni = 0; ni < 4; ++ni)
                    acc[mi][ni] = __builtin_amdgcn_mfma_f32_16x16x32_bf16(
                        af[mi][kk], bg[ni][kk], acc[mi][ni], 0, 0, 0);
        __builtin_amdgcn_s_setprio(0);
        __builtin_amdgcn_s_barrier();
    }

    #pragma unroll
    for (int mi = 0; mi < 4; ++mi) {
        #pragma unroll
        for (int ni = 0; ni < 4; ++ni) {
            const int col = n0 + wn + ni * 16 + l15;
            #pragma unroll
            for (int r = 0; r < 4; ++r) {
                const int rowi = m0 + wm + mi * 16 + 4 * lg + r;
                if constexpr (F32OUT) {
                    Cf[(size_t)rowi * N + col] = acc[mi][ni][r] + bval[ni];
                } else {
                    Cb[(size_t)rowi * N + col] = (short)f2bf(acc[mi][ni][r]);
                }
            }
        }
    }
}

// ---- fused attention (R8-verified): grid 512; 8 waves x 32 q-rows.
// K: global_load_lds direct, chunk-XOR swizzle, double-buffered, gload issued
//    AFTER the barrier into the idle buffer. V: reg-staged transpose into
//    Vt[d][80] with octet swizzle (conflict-free). ONE __syncthreads per tile.
__global__ __launch_bounds__(512, 4) void attn_kernel(
    const short* __restrict__ qkv, short* __restrict__ attn_out)
{
    __shared__ short Kl[2][4096];    // [kv][64] linear, chunk-swizzled
    __shared__ short Vt[2][5120];    // [d][80] octet-swizzled
    const int t    = threadIdx.x;
    const int lane = t & 63;
    const int wid  = t >> 6;
    const int l15  = lane & 15;
    const int lg   = lane >> 4;
    const int pairid = blockIdx.x & 255;
    const int qh  = blockIdx.x >> 8;
    const int bp  = pairid >> 3;
    const int h   = pairid & 7;
    const size_t tok0 = (size_t)bp * 512;
    const int q0   = qh * 256 + wid * 32;
    const int qcol = h * 64;

    bf16x8 qf[2][2];
    #pragma unroll
    for (int mj = 0; mj < 2; ++mj)
        #pragma unroll
        for (int kf = 0; kf < 2; ++kf)
            qf[mj][kf] = *(const bf16x8*)(qkv + (tok0 + q0 + mj * 16 + l15) * 1536
                                          + qcol + kf * 32 + 8 * lg);

    f32x4 ot[4][2];
    #pragma unroll
    for (int i = 0; i < 4; ++i)
        #pragma unroll
        for (int j = 0; j < 2; ++j)
            ot[i][j] = f32x4{0.f, 0.f, 0.f, 0.f};
    float mrun[2] = {-1e30f, -1e30f}, lrun[2] = {0.f, 0.f};

    const int krow = t >> 3;
    const short* Ksrc0 = qkv + (tok0 + krow) * 1536 + 512 + qcol
                         + 8 * ((t & 7) ^ (krow & 7));
    const int sn = t >> 3;
    const int sd = (t & 7) * 8;
    const short* Vsrc0 = qkv + (tok0 + sn) * 1536 + 1024 + qcol + sd;
    const int kvp = (sn & 7) | (((sn >> 3) ^ (t & 7)) << 3);   // swizzled col

    gload16(Ksrc0, &Kl[0][t * 8]);
    bf16x8 vreg = *(const bf16x8*)(Vsrc0);

    const float C = 0.18033688011112042f;   // 0.125 * log2(e)

    for (int tkv = 0; tkv < 8; ++tkv) {
        const int cur = tkv & 1;
        // write V^T tile (register wait on vreg also guarantees K[cur] landed)
        #pragma unroll
        for (int i = 0; i < 8; ++i)
            Vt[cur][(sd + i) * 80 + kvp] = vreg[i];
        __syncthreads();
        // prefetch next tile into the idle buffer (post-barrier: race-free)
        if (tkv < 7) {
            gload16(Ksrc0 + (size_t)(tkv + 1) * 64 * 1536, &Kl[cur ^ 1][t * 8]);
            vreg = *(const bf16x8*)(Vsrc0 + (size_t)(tkv + 1) * 64 * 1536);
        }

        // S^T = K * Q^T  (col m = l15, row n = ni*16 + 4*lg + r), raw scores
        f32x4 st[4][2];
        #pragma unroll
        for (int i = 0; i < 4; ++i)
            #pragma unroll
            for (int j = 0; j < 2; ++j)
                st[i][j] = f32x4{0.f, 0.f, 0.f, 0.f};
        __builtin_amdgcn_s_setprio(1);
        #pragma unroll
        for (int kf = 0; kf < 2; ++kf) {
            #pragma unroll
            for (int ni = 0; ni < 4; ++ni) {
                bf16x8 kfr = *(const bf16x8*)&Kl[cur][
                    (ni * 16 + l15) * 64 + (((kf * 4 + lg) ^ (l15 & 7)) * 8)];
                #pragma unroll
                for (int mj = 0; mj < 2; ++mj)
                    st[ni][mj] = __builtin_amdgcn_mfma_f32_16x16x32_bf16(
                        kfr, qf[mj][kf], st[ni][mj], 0, 0, 0);
            }
        }
        __builtin_amdgcn_s_setprio(0);

        // online softmax (log2 domain); fmax raw, scale once; defer-max THR=8
        #pragma unroll
        for (int mj = 0; mj < 2; ++mj) {
            float pm = -1e30f;
            #pragma unroll
            for (int ni = 0; ni < 4; ++ni)
                #pragma unroll
                for (int r = 0; r < 4; ++r)
                    pm = fmaxf(pm, st[ni][mj][r]);
            pm = fmaxf(pm, __shfl_xor(pm, 16));
            pm = fmaxf(pm, __shfl_xor(pm, 32));
            pm *= C;
            if (!__all(pm <= mrun[mj] + 8.f)) {
                const float mnew = fmaxf(mrun[mj], pm);
                const float fsc  = __builtin_amdgcn_exp2f(mrun[mj] - mnew);
                lrun[mj] *= fsc;
                #pragma unroll
                for (int di = 0; di < 4; ++di) ot[di][mj] *= fsc;
                mrun[mj] = mnew;
            }
            float ps = 0.f;
            #pragma unroll
            for (int ni = 0; ni < 4; ++ni)
                #pragma unroll
                for (int r = 0; r < 4; ++r) {
                    float e = __builtin_amdgcn_exp2f(
                        __builtin_fmaf(st[ni][mj][r], C, -mrun[mj]));
                    st[ni][mj][r] = e;
                    ps += e;
                }
            ps += __shfl_xor(ps, 16);
            ps += __shfl_xor(ps, 32);
            lrun[mj] += ps;
        }

        // O^T += V^T * P^T  (P^T D-frag is the 16x16x16 B-operand layout)
        __builtin_amdgcn_s_setprio(1);
        #pragma unroll
        for (int ni = 0; ni < 4; ++ni) {
            bf16x4 pb[2];
            #pragma unroll
            for (int mj = 0; mj < 2; ++mj)
                #pragma unroll
                for (int r = 0; r < 4; ++r)
                    pb[mj][r] = f2bf_n(st[ni][mj][r]);
            #pragma unroll
            for (int di = 0; di < 4; ++di) {
                const int row = di * 16 + l15;
                bf16x4 av = *(const bf16x4*)&Vt[cur][
                    row * 80
                    + (((2 * ni + (lg >> 1)) ^ (2 * di + (l15 >> 3))) * 8)
                    + 4 * (lg & 1)];
                #pragma unroll
                for (int mj = 0; mj < 2; ++mj)
                    ot[di][mj] = __builtin_amdgcn_mfma_f32_16x16x16bf16_1k(
                        av, pb[mj], ot[di][mj], 0, 0, 0);
            }
        }
        __builtin_amdgcn_s_setprio(0);
    }

    float inv[2];
    #pragma unroll
    for (int mj = 0; mj < 2; ++mj) inv[mj] = 1.f / lrun[mj];
    #pragma unroll
    for (int di = 0; di < 4; ++di)
        #pragma unroll
        for (int mj = 0; mj < 2; ++mj) {
            const size_t tok = tok0 + q0 + mj * 16 + l15;
            const int col = qcol + di * 16 + 4 * lg;
            bf16x4 o4;
            #pragma unroll
            for (int r = 0; r < 4; ++r)
                o4[r] = f2bf_n(ot[di][mj][r] * inv[mj]);
            *(bf16x4*)(attn_out + tok * 512 + col) = o4;
        }
}

extern "C" void kernel_launch(void* const* d_in, const int* in_sizes, int n_in,
                              void* d_out, int out_size, void* d_ws, size_t ws_size,
                              hipStream_t stream) {
    const float* x    = (const float*)d_in[0];   // [16384][512]
    const float* Wqkv = (const float*)d_in[1];   // [512][1536]
    const float* Wout = (const float*)d_in[2];   // [512][512]
    const float* bout = (const float*)d_in[3];   // [512]
    float* out = (float*)d_out;                  // [16384][512] f32

    char* ws = (char*)d_ws;
    short* qkvb  = (short*)(ws);                 // 48 MB  [16384][1536] bf16
    short* xb    = (short*)(ws + 50331648ull);   // 16 MB  [16384][512]  bf16 (x)
    short* attnb = xb;                           // reuse: xb dead before attn writes
    short* Wqkvt = (short*)(ws + 67108864ull);   // 1.5 MB [1536][512]   bf16
    short* Woutt = (short*)(ws + 68681728ull);   // 0.5 MB [512][512]    bf16

    prep_all<<<5120, 256, 0, stream>>>(x, xb, Wqkv, Wout, Wqkvt, Woutt);

    // M=16384 (128 mb) x N=1536 (12 nb) -> 1536 blocks (N fastest)
    gemm_db<0><<<1536, 256, 0, stream>>>(xb, Wqkvt, qkvb, nullptr, nullptr,
                                         16384, 1536, 512, 12);

    attn_kernel<<<512, 512, 0, stream>>>(qkvb, attnb);

    // M=16384 (128 mb) x N=512 (4 nb) -> 512 blocks
    gemm_db<1><<<512, 256, 0, stream>>>(attnb, Woutt, nullptr, out, bout,
                                        16384, 512, 512, 4);
}

// Round 13
// 91.961 us; speedup vs baseline: 1.6700x; 1.0454x over previous
//
#include <hip/hip_runtime.h>
#include <hip/hip_bf16.h>

typedef short bf16x8 __attribute__((ext_vector_type(8)));
typedef short bf16x4 __attribute__((ext_vector_type(4)));
typedef float f32x4  __attribute__((ext_vector_type(4)));
typedef float f32x16 __attribute__((ext_vector_type(16)));

__device__ __forceinline__ unsigned short f2bf(float f) {
    union { float fv; unsigned int u; } v; v.fv = f;
    unsigned int r = v.u + 0x7FFFu + ((v.u >> 16) & 1u);
    return (unsigned short)(r >> 16);
}

__device__ __forceinline__ short f2bf_n(float f) {
    union { __hip_bfloat16 h; short s; } u;
    u.h = __float2bfloat16(f);
    return u.s;
}

__device__ __forceinline__ unsigned int cvtpk(float lo, float hi) {
    unsigned int r;
    asm volatile("v_cvt_pk_bf16_f32 %0, %1, %2" : "=v"(r) : "v"(lo), "v"(hi));
    return r;
}

__device__ __forceinline__ void gload16(const short* g, short* l) {
    __builtin_amdgcn_global_load_lds(
        (const __attribute__((address_space(1))) void*)g,
        (__attribute__((address_space(3))) void*)l, 16, 0, 0);
}

// ---- merged prep: blocks 0..4095 convert x f32->bf16 (8 elems/thread);
//      blocks 4096..5119 transpose+convert the two weight matrices ----
__global__ __launch_bounds__(256) void prep_all(
    const float* __restrict__ x, short* __restrict__ xb,
    const float* __restrict__ Wqkv, const float* __restrict__ Wout,
    short* __restrict__ Wqkvt, short* __restrict__ Woutt)
{
    if (blockIdx.x < 4096) {
        size_t i = ((size_t)blockIdx.x * 256 + threadIdx.x) * 8;
        f32x4 a = *(const f32x4*)(x + i);
        f32x4 b = *(const f32x4*)(x + i + 4);
        bf16x8 s;
        #pragma unroll
        for (int e = 0; e < 4; ++e) { s[e] = (short)f2bf(a[e]); s[4 + e] = (short)f2bf(b[e]); }
        *(bf16x8*)(xb + i) = s;
        return;
    }
    __shared__ float tile[32][33];
    const int b = blockIdx.x - 4096;
    const float* src; short* dst; int N, bb;
    if (b < 768) { src = Wqkv; dst = Wqkvt; N = 1536; bb = b; }
    else         { src = Wout; dst = Woutt; N = 512;  bb = b - 768; }
    const int tx = threadIdx.x;
    const int nb = N >> 5;
    const int k0 = (bb / nb) * 32;
    const int n0 = (bb % nb) * 32;
    const int r  = tx >> 3;
    const int c4 = (tx & 7) * 4;
    f32x4 v = *(const f32x4*)(src + (size_t)(k0 + r) * N + n0 + c4);
    #pragma unroll
    for (int e = 0; e < 4; ++e) tile[r][c4 + e] = v[e];
    __syncthreads();
    bf16x4 o;
    #pragma unroll
    for (int e = 0; e < 4; ++e) o[e] = (short)f2bf(tile[c4 + e][r]);
    *(bf16x4*)(dst + (size_t)(n0 + r) * 512 + k0 + c4) = o;
}

// ---- GEMM: 128x128 tile, double-buffered LDS, counted vmcnt prefetch ----
template<int F32OUT>
__global__ __launch_bounds__(256, 2) void gemm_db(
    const short* __restrict__ A, const short* __restrict__ Bt,
    short* __restrict__ Cb, float* __restrict__ Cf, const float* __restrict__ bias,
    int M, int N, int K, int NB)
{
    __shared__ short lds[2][2][128 * 64];   // [buf][A|B][row*64+chunk*8]
    const int t    = threadIdx.x;
    const int lane = t & 63;
    const int wid  = t >> 6;
    const int l15  = lane & 15;
    const int lg   = lane >> 4;

    const int cpx = gridDim.x >> 3;
    const int swz = (blockIdx.x & 7) * cpx + (blockIdx.x >> 3);
    const int m0 = (swz / NB) * 128;
    const int n0 = (swz % NB) * 128;

    const int wm = (wid >> 1) * 64;
    const int wn = (wid & 1) * 64;

    const int scol = 8 * ((lane & 7) ^ ((lane >> 3) & 7));

    float bval[4];
    if constexpr (F32OUT) {
        #pragma unroll
        for (int ni = 0; ni < 4; ++ni) bval[ni] = bias[n0 + wn + ni * 16 + l15];
    }

    f32x4 acc[4][4];
    #pragma unroll
    for (int i = 0; i < 4; ++i)
        #pragma unroll
        for (int j = 0; j < 4; ++j)
            acc[i][j] = f32x4{0.f, 0.f, 0.f, 0.f};

    const int NT = K >> 6;

    auto stage = [&](int buf, int tk) {
        #pragma unroll
        for (int j = 0; j < 4; ++j) {
            const int r = wid * 32 + j * 8 + (lane >> 3);
            gload16(A  + (size_t)(m0 + r) * K + tk * 64 + scol,
                    &lds[buf][0][(wid * 32 + j * 8) * 64]);
            gload16(Bt + (size_t)(n0 + r) * K + tk * 64 + scol,
                    &lds[buf][1][(wid * 32 + j * 8) * 64]);
        }
    };

    stage(0, 0);

    for (int tk = 0; tk < NT; ++tk) {
        const int cur = tk & 1;
        if (tk + 1 < NT) {
            stage(cur ^ 1, tk + 1);
            asm volatile("s_waitcnt vmcnt(8)" ::: "memory");
        } else {
            asm volatile("s_waitcnt vmcnt(0)" ::: "memory");
        }
        __builtin_amdgcn_s_barrier();

        bf16x8 af[4][2], bg[4][2];
        #pragma unroll
        for (int kk = 0; kk < 2; ++kk) {
            #pragma unroll
            for (int mi = 0; mi < 4; ++mi)
                af[mi][kk] = *(const bf16x8*)&lds[cur][0][
                    (wm + mi * 16 + l15) * 64 + (((kk * 4 + lg) ^ (l15 & 7)) * 8)];
            #pragma unroll
            for (int ni = 0; ni < 4; ++ni)
                bg[ni][kk] = *(const bf16x8*)&lds[cur][1][
                    (wn + ni * 16 + l15) * 64 + (((kk * 4 + lg) ^ (l15 & 7)) * 8)];
        }

        __builtin_amdgcn_s_setprio(1);
        #pragma unroll
        for (int kk = 0; kk < 2; ++kk)
            #pragma unroll
            for (int mi = 0; mi < 4; ++mi)
                #pragma unroll
                for (int ni = 0; ni < 4; ++ni)
                    acc[mi][ni] = __builtin_amdgcn_mfma_f32_16x16x32_bf16(
                        af[mi][kk], bg[ni][kk], acc[mi][ni], 0, 0, 0);
        __builtin_amdgcn_s_setprio(0);
        __builtin_amdgcn_s_barrier();
    }

    #pragma unroll
    for (int mi = 0; mi < 4; ++mi) {
        #pragma unroll
        for (int ni = 0; ni < 4; ++ni) {
            const int col = n0 + wn + ni * 16 + l15;
            #pragma unroll
            for (int r = 0; r < 4; ++r) {
                const int rowi = m0 + wm + mi * 16 + 4 * lg + r;
                if constexpr (F32OUT) {
                    Cf[(size_t)rowi * N + col] = acc[mi][ni][r] + bval[ni];
                } else {
                    Cb[(size_t)rowi * N + col] = (short)f2bf(acc[mi][ni][r]);
                }
            }
        }
    }
}

// ---- fused attention, 32x32 MFMA + in-lane softmax: grid 512, 8 waves x 32 q.
// Lane holds q = lane&31; lanes l / l+32 hold the two kv-halves (hi = lane>>5).
// permlane32_swap HW semantics (LLVM): vdst.lanes[32:63] <-> vsrc.lanes[0:31].
// P B-frag per K=16 slice: swap(vdst=s0a, vsrc=s1a) -> s0a = w0 (hi0: own s0a,
// hi1: partner s1a), s1a = w2 (hi0: partner s0a, hi1: own s1a).  [R11 direction]
// Reduces use __shfl_xor(.,32) — no register-aliasing hazard (R11/R12 bug #2).
__global__ __launch_bounds__(512, 4) void attn_kernel(
    const short* __restrict__ qkv, short* __restrict__ attn_out)
{
    __shared__ short Kl[2][4096];    // [kv][64] linear, chunk-swizzled
    __shared__ short Vt[2][5120];    // [d][80] octet-swizzled
    const int t    = threadIdx.x;
    const int lane = t & 63;
    const int wid  = t >> 6;
    const int l31  = lane & 31;
    const int hi   = lane >> 5;
    const int pairid = blockIdx.x & 255;
    const int qh  = blockIdx.x >> 8;
    const int bp  = pairid >> 3;
    const int h   = pairid & 7;
    const size_t tok0 = (size_t)bp * 512;
    const int q0   = qh * 256 + wid * 32;
    const int qcol = h * 64;

    // Q B-frags (col q = l31, k(d) = 16*kf + 8*hi + e)
    bf16x8 qf[4];
    #pragma unroll
    for (int kf = 0; kf < 4; ++kf)
        qf[kf] = *(const bf16x8*)(qkv + (tok0 + q0 + l31) * 1536
                                  + qcol + kf * 16 + 8 * hi);

    f32x16 ot0, ot1;
    #pragma unroll
    for (int r = 0; r < 16; ++r) { ot0[r] = 0.f; ot1[r] = 0.f; }
    float mrun = -1e30f, lrun = 0.f;

    const int krow = t >> 3;
    const short* Ksrc0 = qkv + (tok0 + krow) * 1536 + 512 + qcol
                         + 8 * ((t & 7) ^ (krow & 7));
    const int sn = t >> 3;
    const int sd = (t & 7) * 8;
    const short* Vsrc0 = qkv + (tok0 + sn) * 1536 + 1024 + qcol + sd;
    const int kvp = (sn & 7) | (((sn >> 3) ^ (t & 7)) << 3);

    gload16(Ksrc0, &Kl[0][t * 8]);
    bf16x8 vreg = *(const bf16x8*)(Vsrc0);

    const float C = 0.18033688011112042f;   // 0.125 * log2(e)

    for (int tkv = 0; tkv < 8; ++tkv) {
        const int cur = tkv & 1;
        #pragma unroll
        for (int i = 0; i < 8; ++i)
            Vt[cur][(sd + i) * 80 + kvp] = vreg[i];
        __syncthreads();
        if (tkv < 7) {
            gload16(Ksrc0 + (size_t)(tkv + 1) * 64 * 1536, &Kl[cur ^ 1][t * 8]);
            vreg = *(const bf16x8*)(Vsrc0 + (size_t)(tkv + 1) * 64 * 1536);
        }

        // QK: st0 = kv 0..31 (rows (r&3)+8*(r>>2)+4*hi), st1 = kv 32..63
        f32x16 st0, st1;
        #pragma unroll
        for (int r = 0; r < 16; ++r) { st0[r] = 0.f; st1[r] = 0.f; }
        __builtin_amdgcn_s_setprio(1);
        #pragma unroll
        for (int kf = 0; kf < 4; ++kf) {
            const int slot = ((2 * kf + hi) ^ (l31 & 7)) * 8;
            bf16x8 k0 = *(const bf16x8*)&Kl[cur][l31 * 64 + slot];
            bf16x8 k1 = *(const bf16x8*)&Kl[cur][(32 + l31) * 64 + slot];
            st0 = __builtin_amdgcn_mfma_f32_32x32x16_bf16(k0, qf[kf], st0, 0, 0, 0);
            st1 = __builtin_amdgcn_mfma_f32_32x32x16_bf16(k1, qf[kf], st1, 0, 0, 0);
        }
        __builtin_amdgcn_s_setprio(0);

        // softmax: in-lane over this lane's 32 rows, cross-half via shfl_xor(32)
        float pm = st0[0];
        #pragma unroll
        for (int r = 1; r < 16; ++r) pm = fmaxf(pm, st0[r]);
        #pragma unroll
        for (int r = 0; r < 16; ++r) pm = fmaxf(pm, st1[r]);
        pm = fmaxf(pm, __shfl_xor(pm, 32));
        pm *= C;
        if (!__all(pm <= mrun + 8.f)) {
            const float mnew = fmaxf(mrun, pm);
            const float fsc  = __builtin_amdgcn_exp2f(mrun - mnew);
            lrun *= fsc;
            #pragma unroll
            for (int r = 0; r < 16; ++r) { ot0[r] *= fsc; ot1[r] *= fsc; }
            mrun = mnew;
        }
        float ps = 0.f;
        #pragma unroll
        for (int r = 0; r < 16; ++r) {
            st0[r] = __builtin_amdgcn_exp2f(__builtin_fmaf(st0[r], C, -mrun));
            ps += st0[r];
        }
        #pragma unroll
        for (int r = 0; r < 16; ++r) {
            st1[r] = __builtin_amdgcn_exp2f(__builtin_fmaf(st1[r], C, -mrun));
            ps += st1[r];
        }
        ps += __shfl_xor(ps, 32);
        lrun += ps;

        // PV: per ks (kv 16-slice): build P B-frag, 2 MFMAs over d-blocks.
        // swap(vdst=s0a, vsrc=s1a): s0a -> w0, s1a -> w2 (vdst.hi <-> vsrc.lo).
        __builtin_amdgcn_s_setprio(1);
#define PVKS(KS, ST)                                                          \
        {                                                                     \
            const int a8 = ((KS) & 1) * 8;                                    \
            unsigned int s0a = cvtpk(ST[a8 + 0], ST[a8 + 1]);                 \
            unsigned int s0b = cvtpk(ST[a8 + 2], ST[a8 + 3]);                 \
            unsigned int s1a = cvtpk(ST[a8 + 4], ST[a8 + 5]);                 \
            unsigned int s1b = cvtpk(ST[a8 + 6], ST[a8 + 7]);                 \
            asm volatile("v_permlane32_swap_b32 %0, %1"                       \
                         : "+v"(s0a), "+v"(s1a));                             \
            asm volatile("v_permlane32_swap_b32 %0, %1"                       \
                         : "+v"(s0b), "+v"(s1b));                             \
            union { unsigned int w[4]; bf16x8 v; } pu;                        \
            pu.w[0] = s0a; pu.w[1] = s0b; pu.w[2] = s1a; pu.w[3] = s1b;       \
            {                                                                 \
                const int sl0 = ((2 * (KS) + hi) ^ (l31 >> 3)) * 8;           \
                bf16x8 vf = *(const bf16x8*)&Vt[cur][l31 * 80 + sl0];         \
                ot0 = __builtin_amdgcn_mfma_f32_32x32x16_bf16(                \
                    vf, pu.v, ot0, 0, 0, 0);                                  \
            }                                                                 \
            {                                                                 \
                const int sl1 = ((2 * (KS) + hi) ^ (4 ^ (l31 >> 3))) * 8;     \
                bf16x8 vf = *(const bf16x8*)&Vt[cur][(32 + l31) * 80 + sl1];  \
                ot1 = __builtin_amdgcn_mfma_f32_32x32x16_bf16(                \
                    vf, pu.v, ot1, 0, 0, 0);                                  \
            }                                                                 \
        }
        PVKS(0, st0)
        PVKS(1, st0)
        PVKS(2, st1)
        PVKS(3, st1)
#undef PVKS
        __builtin_amdgcn_s_setprio(0);
    }

    const float inv = 1.f / lrun;
    short* obase = attn_out + (tok0 + q0 + l31) * 512 + qcol + 4 * hi;
    #pragma unroll
    for (int rq = 0; rq < 4; ++rq) {
        bf16x4 o0, o1;
        #pragma unroll
        for (int j = 0; j < 4; ++j) {
            o0[j] = f2bf_n(ot0[4 * rq + j] * inv);
            o1[j] = f2bf_n(ot1[4 * rq + j] * inv);
        }
        *(bf16x4*)(obase + rq * 8)      = o0;
        *(bf16x4*)(obase + 32 + rq * 8) = o1;
    }
}

extern "C" void kernel_launch(void* const* d_in, const int* in_sizes, int n_in,
                              void* d_out, int out_size, void* d_ws, size_t ws_size,
                              hipStream_t stream) {
    const float* x    = (const float*)d_in[0];   // [16384][512]
    const float* Wqkv = (const float*)d_in[1];   // [512][1536]
    const float* Wout = (const float*)d_in[2];   // [512][512]
    const float* bout = (const float*)d_in[3];   // [512]
    float* out = (float*)d_out;                  // [16384][512] f32

    char* ws = (char*)d_ws;
    short* qkvb  = (short*)(ws);                 // 48 MB  [16384][1536] bf16
    short* xb    = (short*)(ws + 50331648ull);   // 16 MB  [16384][512]  bf16 (x)
    short* attnb = xb;                           // reuse: xb dead before attn writes
    short* Wqkvt = (short*)(ws + 67108864ull);   // 1.5 MB [1536][512]   bf16
    short* Woutt = (short*)(ws + 68681728ull);   // 0.5 MB [512][512]    bf16

    prep_all<<<5120, 256, 0, stream>>>(x, xb, Wqkv, Wout, Wqkvt, Woutt);

    // M=16384 (128 mb) x N=1536 (12 nb) -> 1536 blocks (N fastest)
    gemm_db<0><<<1536, 256, 0, stream>>>(xb, Wqkvt, qkvb, nullptr, nullptr,
                                         16384, 1536, 512, 12);

    attn_kernel<<<512, 512, 0, stream>>>(qkvb, attnb);

    // M=16384 (128 mb) x N=512 (4 nb) -> 512 blocks
    gemm_db<1><<<512, 256, 0, stream>>>(attnb, Woutt, nullptr, out, bout,
                                        16384, 512, 512, 4);
}